// Round 5
// baseline (168.048 us; speedup 1.0000x reference)
//
#include <hip/hip_runtime.h>
#include <stdint.h>

// ---------- types ----------
typedef __bf16 bf16x8 __attribute__((ext_vector_type(8)));
typedef float  f32x4  __attribute__((ext_vector_type(4)));

__device__ __forceinline__ unsigned short f2bf(float f) {
  union { float f; unsigned int u; } v; v.f = f;
  unsigned int r = v.u + 0x7FFFu + ((v.u >> 16) & 1u);   // RNE
  return (unsigned short)(r >> 16);
}
__device__ __forceinline__ float bf2f(unsigned short b) {
  union { unsigned int u; float f; } v; v.u = ((unsigned int)b) << 16; return v.f;
}

__device__ __forceinline__ void gld_lds16(const unsigned short* g, unsigned short* l) {
  __builtin_amdgcn_global_load_lds(
      (const __attribute__((address_space(1))) void*)g,
      (__attribute__((address_space(3))) void*)l, 16, 0, 0);
}

__device__ __forceinline__ int swz(int row) { return (row & 3) ^ ((row >> 2) & 3); }

// ---------- fused: Y -> Yb + Ybt (y<16); W -> Wb (y==16); x==0,y==16 zeros stats ----------
__global__ __launch_bounds__(256) void convert_all(
    const float* __restrict__ Y, unsigned short* __restrict__ Yb,
    unsigned short* __restrict__ Ybt, const float4* __restrict__ W,
    ushort4* __restrict__ Wb, float* __restrict__ stats /*diag+l+flags*/) {
  if (blockIdx.y == 16) {   // W conversion: 64 blocks x 256 thr x 16 float4
    if (blockIdx.x == 0) {  // zero diag(4096f)+l(4096f)+flags(64u) = 8256 dwords
      for (int i = threadIdx.x; i < 8256; i += 256) ((unsigned int*)stats)[i] = 0u;
    }
    const int base = blockIdx.x * 4096 + threadIdx.x;
#pragma unroll
    for (int k = 0; k < 16; k++) {
      float4 f = W[base + k * 256];
      ushort4 o;
      o.x = f2bf(f.x); o.y = f2bf(f.y); o.z = f2bf(f.z); o.w = f2bf(f.w);
      Wb[base + k * 256] = o;
    }
    return;
  }
  __shared__ unsigned short tile[64][65];
  const int r0 = blockIdx.x * 64;
  const int c0 = blockIdx.y * 64;
  const int tx = threadIdx.x & 63, ty = threadIdx.x >> 6;
#pragma unroll
  for (int k = 0; k < 16; k++) {
    const int r = ty + 4 * k;
    float f = Y[(long)(r0 + r) * 1024 + c0 + tx];
    unsigned short b = f2bf(f);
    Yb[(long)(r0 + r) * 1024 + c0 + tx] = b;
    tile[r][tx] = b;
  }
  __syncthreads();
#pragma unroll
  for (int k = 0; k < 16; k++) {
    const int c = ty + 4 * k;
    Ybt[(long)(c0 + c) * 4096 + r0 + tx] = tile[tx][c];
  }
}

// ---------- GEMM1 fused: G = Yb * Wb^T (bf16 out) + diag[i] += ||G_i tile||^2 ----------
__global__ __launch_bounds__(256) void gemm1_fused(
    const unsigned short* __restrict__ A, const unsigned short* __restrict__ B,
    unsigned short* __restrict__ G, float* __restrict__ diag) {
  __shared__ __align__(16) unsigned short smA[128 * 32];
  __shared__ __align__(16) unsigned short smB[64 * 32];
  const int tid = threadIdx.x, lane = tid & 63, wave = tid >> 6;
  const int waveM = wave >> 1, waveN = wave & 1;
  const long rowA0 = (long)blockIdx.y * 128;
  const long rowB0 = (long)blockIdx.x * 64;

  const int rS = tid >> 2;
  const int kS = (tid & 3) ^ swz(rS);
  const unsigned short* gA0 = A + (rowA0 + rS) * 1024 + kS * 8;
  const unsigned short* gA1 = gA0 + 64 * 1024;
  unsigned short* lA0 = &smA[tid * 8];
  const unsigned short* gB0 = B + (rowB0 + rS) * 1024 + kS * 8;
  unsigned short* lB0 = &smB[tid * 8];

  const int ra = waveM * 64 + (lane & 15);
  const int rb = waveN * 32 + (lane & 15);
  const unsigned short* pa = &smA[(ra * 4 + ((lane >> 4) ^ swz(ra))) * 8];
  const unsigned short* pb = &smB[(rb * 4 + ((lane >> 4) ^ swz(rb))) * 8];

  f32x4 acc[4][2];
#pragma unroll
  for (int i = 0; i < 4; i++)
#pragma unroll
    for (int j = 0; j < 2; j++)
#pragma unroll
      for (int r = 0; r < 4; r++) acc[i][j][r] = 0.f;

  for (int k0 = 0; k0 < 1024; k0 += 32) {
    __syncthreads();
    gld_lds16(gA0 + k0, lA0);
    gld_lds16(gA1 + k0, lA0 + 2048);
    gld_lds16(gB0 + k0, lB0);
    __syncthreads();
    bf16x8 af[4], bfv[2];
#pragma unroll
    for (int i = 0; i < 4; i++) af[i] = *(const bf16x8*)(pa + i * 512);
#pragma unroll
    for (int j = 0; j < 2; j++) bfv[j] = *(const bf16x8*)(pb + j * 512);
#pragma unroll
    for (int mi = 0; mi < 4; mi++)
#pragma unroll
      for (int ni = 0; ni < 2; ni++)
        acc[mi][ni] = __builtin_amdgcn_mfma_f32_16x16x32_bf16(af[mi], bfv[ni], acc[mi][ni], 0, 0, 0);
  }

  const long row0 = rowA0 + waveM * 64 + (lane >> 4) * 4;
  const long col0 = rowB0 + waveN * 32 + (lane & 15);
  float nsum[4][4];
#pragma unroll
  for (int mi = 0; mi < 4; mi++)
#pragma unroll
    for (int r = 0; r < 4; r++) nsum[mi][r] = 0.f;
#pragma unroll
  for (int mi = 0; mi < 4; mi++)
#pragma unroll
    for (int ni = 0; ni < 2; ni++)
#pragma unroll
      for (int r = 0; r < 4; r++) {
        unsigned short g16 = f2bf(acc[mi][ni][r]);
        G[(row0 + mi * 16 + r) * 1024 + col0 + ni * 16] = g16;
        float gv = bf2f(g16);
        nsum[mi][r] += gv * gv;
      }
#pragma unroll
  for (int off = 1; off < 16; off <<= 1)
#pragma unroll
    for (int mi = 0; mi < 4; mi++)
#pragma unroll
      for (int r = 0; r < 4; r++) nsum[mi][r] += __shfl_xor(nsum[mi][r], off, 64);
  if ((lane & 15) == 0) {
#pragma unroll
    for (int mi = 0; mi < 4; mi++)
#pragma unroll
      for (int r = 0; r < 4; r++)
        atomicAdd(&diag[row0 + mi * 16 + r], nsum[mi][r]);
  }
}

// ---------- GEMM2 symmetric, 128x64 tiles, dense 1D triangle grid (1056 blocks).
// Kept tiles: bc >= 2*br. Normal epilogue always; mirror only for bc >= 2br+2
// (diagonal square fully covered by its two normal tiles; no dup writes/sums). ----------
__global__ __launch_bounds__(256) void gemm2_sym(
    const unsigned short* __restrict__ G, const float* __restrict__ diag,
    unsigned short* __restrict__ P, float* __restrict__ l,
    unsigned int* __restrict__ flags) {
  // linear t -> (br, bc); C(br) = br*(65-br)
  const int t = blockIdx.x;
  int br = (int)((65.0f - sqrtf(4225.0f - 4.0f * (float)t)) * 0.5f);
  while (br * (65 - br) > t) --br;
  while ((br + 1) * (64 - br) <= t) ++br;
  const int bc = 2 * br + (t - br * (65 - br));

  __shared__ __align__(16) unsigned short smA[128 * 32];
  __shared__ __align__(16) unsigned short smB[64 * 32];
  const int tid = threadIdx.x, lane = tid & 63, wave = tid >> 6;
  const int waveM = wave >> 1, waveN = wave & 1;
  const long rowA0 = (long)br * 128;   // rows R
  const long rowB0 = (long)bc * 64;    // cols C (rows of G as B)

  const int rS = tid >> 2;
  const int kS = (tid & 3) ^ swz(rS);
  const unsigned short* gA0 = G + (rowA0 + rS) * 1024 + kS * 8;
  const unsigned short* gA1 = gA0 + 64 * 1024;
  unsigned short* lA0 = &smA[tid * 8];
  const unsigned short* gB0 = G + (rowB0 + rS) * 1024 + kS * 8;
  unsigned short* lB0 = &smB[tid * 8];

  const int ra = waveM * 64 + (lane & 15);
  const int rb = waveN * 32 + (lane & 15);
  const unsigned short* pa = &smA[(ra * 4 + ((lane >> 4) ^ swz(ra))) * 8];
  const unsigned short* pb = &smB[(rb * 4 + ((lane >> 4) ^ swz(rb))) * 8];

  f32x4 acc[4][2];
#pragma unroll
  for (int i = 0; i < 4; i++)
#pragma unroll
    for (int j = 0; j < 2; j++)
#pragma unroll
      for (int r = 0; r < 4; r++) acc[i][j][r] = 0.f;

  for (int k0 = 0; k0 < 1024; k0 += 32) {
    __syncthreads();
    gld_lds16(gA0 + k0, lA0);
    gld_lds16(gA1 + k0, lA0 + 2048);
    gld_lds16(gB0 + k0, lB0);
    __syncthreads();
    bf16x8 af[4], bfv[2];
#pragma unroll
    for (int i = 0; i < 4; i++) af[i] = *(const bf16x8*)(pa + i * 512);
#pragma unroll
    for (int j = 0; j < 2; j++) bfv[j] = *(const bf16x8*)(pb + j * 512);
#pragma unroll
    for (int mi = 0; mi < 4; mi++)
#pragma unroll
      for (int ni = 0; ni < 2; ni++)
        acc[mi][ni] = __builtin_amdgcn_mfma_f32_16x16x32_bf16(af[mi], bfv[ni], acc[mi][ni], 0, 0, 0);
  }

  const long row0 = rowA0 + waveM * 64 + (lane >> 4) * 4;  // 4 rows x4 mi held
  const long col0 = rowB0 + waveN * 32 + (lane & 15);      // 1 col x2 ni held

  // ---- normal epilogue: P[row, col] = exp(acc - d_row), rowsums -> l ----
  float drow[4][4], lsum[4][4];
#pragma unroll
  for (int mi = 0; mi < 4; mi++)
#pragma unroll
    for (int r = 0; r < 4; r++) {
      drow[mi][r] = diag[row0 + mi * 16 + r];
      lsum[mi][r] = 0.f;
    }
  unsigned int nz = 0;
#pragma unroll
  for (int mi = 0; mi < 4; mi++)
#pragma unroll
    for (int ni = 0; ni < 2; ni++)
#pragma unroll
      for (int r = 0; r < 4; r++) {
        float pv = __expf(acc[mi][ni][r] - drow[mi][r]);
        unsigned short p16 = f2bf(pv);
        nz |= p16;
        lsum[mi][r] += bf2f(p16);
        P[(row0 + mi * 16 + r) * 4096 + col0 + ni * 16] = p16;
      }
#pragma unroll
  for (int off = 1; off < 16; off <<= 1)
#pragma unroll
    for (int mi = 0; mi < 4; mi++)
#pragma unroll
      for (int r = 0; r < 4; r++) lsum[mi][r] += __shfl_xor(lsum[mi][r], off, 64);
  if ((lane & 15) == 0) {
#pragma unroll
    for (int mi = 0; mi < 4; mi++)
#pragma unroll
      for (int r = 0; r < 4; r++)
        atomicAdd(&l[row0 + mi * 16 + r], lsum[mi][r]);
  }
  if (__ballot(nz != 0)) {
    if (lane == 0)
      atomicOr(&flags[br * 2 + (bc >> 5)], 1u << (bc & 31));
  }

  // ---- mirror epilogue (bc >= 2br+2): P[col, row] = exp(acc - d_col) ----
  if (bc >= 2 * br + 2) {
    float dcol[2], csum[2];
#pragma unroll
    for (int ni = 0; ni < 2; ni++) {
      dcol[ni] = diag[col0 + ni * 16];
      csum[ni] = 0.f;
    }
    unsigned int nzm = 0;
#pragma unroll
    for (int mi = 0; mi < 4; mi++)
#pragma unroll
      for (int ni = 0; ni < 2; ni++) {
        ushort4 o;
        unsigned short x;
        float pv;
        pv = __expf(acc[mi][ni][0] - dcol[ni]); x = f2bf(pv); nzm |= x; csum[ni] += bf2f(x); o.x = x;
        pv = __expf(acc[mi][ni][1] - dcol[ni]); x = f2bf(pv); nzm |= x; csum[ni] += bf2f(x); o.y = x;
        pv = __expf(acc[mi][ni][2] - dcol[ni]); x = f2bf(pv); nzm |= x; csum[ni] += bf2f(x); o.z = x;
        pv = __expf(acc[mi][ni][3] - dcol[ni]); x = f2bf(pv); nzm |= x; csum[ni] += bf2f(x); o.w = x;
        *(ushort4*)(P + (col0 + ni * 16) * 4096 + row0 + mi * 16) = o;
      }
    // reduce over the 4 lanes sharing each col within this wave (lane>>4 varies)
#pragma unroll
    for (int ni = 0; ni < 2; ni++) {
      csum[ni] += __shfl_xor(csum[ni], 16, 64);
      csum[ni] += __shfl_xor(csum[ni], 32, 64);
    }
    if (lane < 16) {
#pragma unroll
      for (int ni = 0; ni < 2; ni++)
        atomicAdd(&l[col0 + ni * 16], csum[ni]);   // per wave: rows-half sum
    }
    if (__ballot(nzm != 0)) {
      if (lane == 0) {
        const int bit = 2 * br + waveM;            // col-tile of mirror rows
        atomicOr(&flags[(bc >> 1) * 2 + (bit >> 5)], 1u << (bit & 31));
      }
    }
  }
}

// ---------- GEMM3 sparse: Z = (P @ Y) / l, skipping all-zero P tiles (exact) ----------
__global__ __launch_bounds__(256) void gemm3_sparse(
    const unsigned short* __restrict__ P, const unsigned short* __restrict__ Ybt,
    const float* __restrict__ l, const unsigned int* __restrict__ flags,
    float* __restrict__ Z) {
  __shared__ __align__(16) unsigned short smA[128 * 32];
  __shared__ __align__(16) unsigned short smB[64 * 32];
  const int tid = threadIdx.x, lane = tid & 63, wave = tid >> 6;
  const int waveM = wave >> 1, waveN = wave & 1;
  const long rowA0 = (long)blockIdx.y * 128;
  const long rowB0 = (long)blockIdx.x * 64;

  const int rS = tid >> 2;
  const int kS = (tid & 3) ^ swz(rS);
  const unsigned short* gA0 = P + (rowA0 + rS) * 4096 + kS * 8;
  const unsigned short* gA1 = gA0 + 64 * 4096;
  unsigned short* lA0 = &smA[tid * 8];
  const unsigned short* gB0 = Ybt + (rowB0 + rS) * 4096 + kS * 8;
  unsigned short* lB0 = &smB[tid * 8];

  const int ra = waveM * 64 + (lane & 15);
  const int rb = waveN * 32 + (lane & 15);
  const unsigned short* pa = &smA[(ra * 4 + ((lane >> 4) ^ swz(ra))) * 8];
  const unsigned short* pb = &smB[(rb * 4 + ((lane >> 4) ^ swz(rb))) * 8];

  const unsigned int f0 = flags[blockIdx.y * 2];
  const unsigned int f1 = flags[blockIdx.y * 2 + 1];

  f32x4 acc[4][2];
#pragma unroll
  for (int i = 0; i < 4; i++)
#pragma unroll
    for (int j = 0; j < 2; j++)
#pragma unroll
      for (int r = 0; r < 4; r++) acc[i][j][r] = 0.f;

  for (int t = 0; t < 64; ++t) {
    const unsigned int bit = (t < 32) ? ((f0 >> t) & 1u) : ((f1 >> (t - 32)) & 1u);
    if (!bit) continue;
#pragma unroll
    for (int kk = 0; kk < 2; ++kk) {
      const int k0 = t * 64 + kk * 32;
      __syncthreads();
      gld_lds16(gA0 + k0, lA0);
      gld_lds16(gA1 + k0, lA0 + 2048);
      gld_lds16(gB0 + k0, lB0);
      __syncthreads();
      bf16x8 af[4], bfv[2];
#pragma unroll
      for (int i = 0; i < 4; i++) af[i] = *(const bf16x8*)(pa + i * 512);
#pragma unroll
      for (int j = 0; j < 2; j++) bfv[j] = *(const bf16x8*)(pb + j * 512);
#pragma unroll
      for (int mi = 0; mi < 4; mi++)
#pragma unroll
        for (int ni = 0; ni < 2; ni++)
          acc[mi][ni] = __builtin_amdgcn_mfma_f32_16x16x32_bf16(af[mi], bfv[ni], acc[mi][ni], 0, 0, 0);
    }
  }

  const long row0 = rowA0 + waveM * 64 + (lane >> 4) * 4;
  const long col0 = rowB0 + waveN * 32 + (lane & 15);
#pragma unroll
  for (int mi = 0; mi < 4; mi++)
#pragma unroll
    for (int r = 0; r < 4; r++) {
      const long row = row0 + mi * 16 + r;
      const float inv = 1.f / l[row];
#pragma unroll
      for (int ni = 0; ni < 2; ni++)
        Z[row * 1024 + col0 + ni * 16] = acc[mi][ni][r] * inv;
    }
}

// ---------- launch ----------
extern "C" void kernel_launch(void* const* d_in, const int* in_sizes, int n_in,
                              void* d_out, int out_size, void* d_ws, size_t ws_size,
                              hipStream_t stream) {
  const float* Y = (const float*)d_in[0];   // 4096 x 1024
  const float* W = (const float*)d_in[1];   // 1024 x 1024
  float* Z = (float*)d_out;                 // 4096 x 1024 fp32

  uint8_t* w = (uint8_t*)d_ws;
  unsigned short* Yb   = (unsigned short*)(w);                         // 8 MB
  unsigned short* Ybt  = (unsigned short*)(w + (8ull  << 20));         // 8 MB
  unsigned short* Wb   = (unsigned short*)(w + (16ull << 20));         // 2 MB
  unsigned short* Gb   = (unsigned short*)(w + (18ull << 20));         // 8 MB
  unsigned short* P    = (unsigned short*)(w + (26ull << 20));         // 32 MB
  float*          diag = (float*)         (w + (58ull << 20));         // 16 KB
  float*          lrow = (float*)         (w + (58ull << 20) + 16384); // 16 KB
  unsigned int*   flg  = (unsigned int*)  (w + (58ull << 20) + 32768); // 256 B

  // stats (diag+l+flags) zeroed inside convert_all block (y==16, x==0)
  convert_all<<<dim3(64, 17), 256, 0, stream>>>(Y, Yb, Ybt, (const float4*)W,
                                                (ushort4*)Wb, diag);

  // G = Y * W^T (bf16) + diag accumulation
  gemm1_fused<<<dim3(16, 32), 256, 0, stream>>>(Yb, Wb, Gb, diag);

  // P = exp(G G^T - diag[row]); dense triangle grid, 128x64 tiles
  gemm2_sym<<<1056, 256, 0, stream>>>(Gb, diag, P, lrow, flg);

  // Z = (P @ Y) / l with exact zero-tile skipping
  gemm3_sparse<<<dim3(16, 32), 256, 0, stream>>>(P, Ybt, lrow, flg, Z);
}

// Round 6
// 152.428 us; speedup vs baseline: 1.1025x; 1.1025x over previous
//
#include <hip/hip_runtime.h>
#include <stdint.h>

// ---------- types ----------
typedef __bf16 bf16x8 __attribute__((ext_vector_type(8)));
typedef float  f32x4  __attribute__((ext_vector_type(4)));

__device__ __forceinline__ unsigned short f2bf(float f) {
  union { float f; unsigned int u; } v; v.f = f;
  unsigned int r = v.u + 0x7FFFu + ((v.u >> 16) & 1u);   // RNE
  return (unsigned short)(r >> 16);
}
__device__ __forceinline__ float bf2f(unsigned short b) {
  union { unsigned int u; float f; } v; v.u = ((unsigned int)b) << 16; return v.f;
}

__device__ __forceinline__ void gld_lds16(const unsigned short* g, unsigned short* l) {
  __builtin_amdgcn_global_load_lds(
      (const __attribute__((address_space(1))) void*)g,
      (__attribute__((address_space(3))) void*)l, 16, 0, 0);
}

__device__ __forceinline__ int swz(int row) { return (row & 3) ^ ((row >> 2) & 3); }

// ---------- fused: Y -> Yb + Ybt (y<16); W -> Wb (y==16); x==0,y==16 zeros stats ----------
__global__ __launch_bounds__(256) void convert_all(
    const float* __restrict__ Y, unsigned short* __restrict__ Yb,
    unsigned short* __restrict__ Ybt, const float4* __restrict__ W,
    ushort4* __restrict__ Wb, float* __restrict__ stats /*diag+l+flags*/) {
  if (blockIdx.y == 16) {
    if (blockIdx.x == 0) {  // zero diag(4096f)+l(4096f)+flags(64u)
      for (int i = threadIdx.x; i < 8256; i += 256) ((unsigned int*)stats)[i] = 0u;
    }
    const int base = blockIdx.x * 4096 + threadIdx.x;
#pragma unroll
    for (int k = 0; k < 16; k++) {
      float4 f = W[base + k * 256];
      ushort4 o;
      o.x = f2bf(f.x); o.y = f2bf(f.y); o.z = f2bf(f.z); o.w = f2bf(f.w);
      Wb[base + k * 256] = o;
    }
    return;
  }
  __shared__ unsigned short tile[64][65];
  const int r0 = blockIdx.x * 64;
  const int c0 = blockIdx.y * 64;
  const int tx = threadIdx.x & 63, ty = threadIdx.x >> 6;
#pragma unroll
  for (int k = 0; k < 16; k++) {
    const int r = ty + 4 * k;
    float f = Y[(long)(r0 + r) * 1024 + c0 + tx];
    unsigned short b = f2bf(f);
    Yb[(long)(r0 + r) * 1024 + c0 + tx] = b;
    tile[r][tx] = b;
  }
  __syncthreads();
#pragma unroll
  for (int k = 0; k < 16; k++) {
    const int c = ty + 4 * k;
    Ybt[(long)(c0 + c) * 4096 + r0 + tx] = tile[tx][c];
  }
}

// ---------- GEMM1 fused: G = Yb * Wb^T (bf16) + diag, 128x64 tile, BK=64 ----------
__global__ __launch_bounds__(256) void gemm1_fused(
    const unsigned short* __restrict__ A, const unsigned short* __restrict__ B,
    unsigned short* __restrict__ G, float* __restrict__ diag) {
  __shared__ __align__(16) unsigned short smA[128 * 64];   // 16 KB
  __shared__ __align__(16) unsigned short smB[64 * 64];    // 8 KB
  const int tid = threadIdx.x, lane = tid & 63, wave = tid >> 6;
  const int waveM = wave >> 1, waveN = wave & 1;
  const long rowA0 = (long)blockIdx.y * 128;
  const long rowB0 = (long)blockIdx.x * 64;

  // staging: chunk c (16B) -> LDS slot c; global kc = (c&7)^(row&7), row = c>>3
  const unsigned short* gAq[4]; unsigned short* lAq[4];
  const unsigned short* gBq[2]; unsigned short* lBq[2];
#pragma unroll
  for (int q = 0; q < 4; q++) {
    const int c = tid + q * 256, row = c >> 3, kc = (c & 7) ^ (row & 7);
    gAq[q] = A + (rowA0 + row) * 1024 + kc * 8;
    lAq[q] = &smA[c * 8];
  }
#pragma unroll
  for (int q = 0; q < 2; q++) {
    const int c = tid + q * 256, row = c >> 3, kc = (c & 7) ^ (row & 7);
    gBq[q] = B + (rowB0 + row) * 1024 + kc * 8;
    lBq[q] = &smB[c * 8];
  }

  // fragment bases: row&7 == lane&7 for all fragment rows
  const unsigned short* paB = &smA[(waveM * 64 + (lane & 15)) * 64];
  const unsigned short* pbB = &smB[(waveN * 32 + (lane & 15)) * 64];
  const int g = lane >> 4, s = lane & 7;
  const int ko[2] = { ((0 * 4 + g) ^ s) * 8, ((1 * 4 + g) ^ s) * 8 };

  f32x4 acc[4][2];
#pragma unroll
  for (int i = 0; i < 4; i++)
#pragma unroll
    for (int j = 0; j < 2; j++)
#pragma unroll
      for (int r = 0; r < 4; r++) acc[i][j][r] = 0.f;

  for (int k0 = 0; k0 < 1024; k0 += 64) {
    __syncthreads();
#pragma unroll
    for (int q = 0; q < 4; q++) gld_lds16(gAq[q] + k0, lAq[q]);
#pragma unroll
    for (int q = 0; q < 2; q++) gld_lds16(gBq[q] + k0, lBq[q]);
    __syncthreads();
#pragma unroll
    for (int kk = 0; kk < 2; kk++) {
      bf16x8 af[4], bfv[2];
#pragma unroll
      for (int i = 0; i < 4; i++) af[i] = *(const bf16x8*)(paB + i * 1024 + ko[kk]);
#pragma unroll
      for (int j = 0; j < 2; j++) bfv[j] = *(const bf16x8*)(pbB + j * 1024 + ko[kk]);
#pragma unroll
      for (int mi = 0; mi < 4; mi++)
#pragma unroll
        for (int ni = 0; ni < 2; ni++)
          acc[mi][ni] = __builtin_amdgcn_mfma_f32_16x16x32_bf16(af[mi], bfv[ni], acc[mi][ni], 0, 0, 0);
    }
  }

  const long row0 = rowA0 + waveM * 64 + (lane >> 4) * 4;
  const long col0 = rowB0 + waveN * 32 + (lane & 15);
  float nsum[4][4];
#pragma unroll
  for (int mi = 0; mi < 4; mi++)
#pragma unroll
    for (int r = 0; r < 4; r++) nsum[mi][r] = 0.f;
#pragma unroll
  for (int mi = 0; mi < 4; mi++)
#pragma unroll
    for (int ni = 0; ni < 2; ni++)
#pragma unroll
      for (int r = 0; r < 4; r++) {
        unsigned short g16 = f2bf(acc[mi][ni][r]);
        G[(row0 + mi * 16 + r) * 1024 + col0 + ni * 16] = g16;
        float gv = bf2f(g16);
        nsum[mi][r] += gv * gv;
      }
#pragma unroll
  for (int off = 1; off < 16; off <<= 1)
#pragma unroll
    for (int mi = 0; mi < 4; mi++)
#pragma unroll
      for (int r = 0; r < 4; r++) nsum[mi][r] += __shfl_xor(nsum[mi][r], off, 64);
  if ((lane & 15) == 0) {
#pragma unroll
    for (int mi = 0; mi < 4; mi++)
#pragma unroll
      for (int r = 0; r < 4; r++)
        atomicAdd(&diag[row0 + mi * 16 + r], nsum[mi][r]);
  }
}

// ---------- GEMM2 symmetric: 128x128 tile, BK=64, dense triangle grid (528).
// br <= bc; normal epilogue always, mirror epilogue when bc > br. ----------
__global__ __launch_bounds__(256) void gemm2_sym(
    const unsigned short* __restrict__ G, const float* __restrict__ diag,
    unsigned short* __restrict__ P, float* __restrict__ l,
    unsigned int* __restrict__ flags) {
  int rem = blockIdx.x, br = 0;
  while (rem >= 32 - br) { rem -= 32 - br; ++br; }
  const int bc = br + rem;

  __shared__ __align__(16) unsigned short smA[128 * 64];   // 16 KB
  __shared__ __align__(16) unsigned short smB[128 * 64];   // 16 KB
  const int tid = threadIdx.x, lane = tid & 63, wave = tid >> 6;
  const int waveM = wave >> 1, waveN = wave & 1;
  const long rowA0 = (long)br * 128;
  const long rowB0 = (long)bc * 128;

  const unsigned short* gAq[4]; unsigned short* lAq[4];
  const unsigned short* gBq[4]; unsigned short* lBq[4];
#pragma unroll
  for (int q = 0; q < 4; q++) {
    const int c = tid + q * 256, row = c >> 3, kc = (c & 7) ^ (row & 7);
    gAq[q] = G + (rowA0 + row) * 1024 + kc * 8;
    gBq[q] = G + (rowB0 + row) * 1024 + kc * 8;
    lAq[q] = &smA[c * 8];
    lBq[q] = &smB[c * 8];
  }

  const unsigned short* paB = &smA[(waveM * 64 + (lane & 15)) * 64];
  const unsigned short* pbB = &smB[(waveN * 64 + (lane & 15)) * 64];
  const int g = lane >> 4, s = lane & 7;
  const int ko[2] = { ((0 * 4 + g) ^ s) * 8, ((1 * 4 + g) ^ s) * 8 };

  f32x4 acc[4][4];
#pragma unroll
  for (int i = 0; i < 4; i++)
#pragma unroll
    for (int j = 0; j < 4; j++)
#pragma unroll
      for (int r = 0; r < 4; r++) acc[i][j][r] = 0.f;

  for (int k0 = 0; k0 < 1024; k0 += 64) {
    __syncthreads();
#pragma unroll
    for (int q = 0; q < 4; q++) gld_lds16(gAq[q] + k0, lAq[q]);
#pragma unroll
    for (int q = 0; q < 4; q++) gld_lds16(gBq[q] + k0, lBq[q]);
    __syncthreads();
#pragma unroll
    for (int kk = 0; kk < 2; kk++) {
      bf16x8 af[4], bfv[4];
#pragma unroll
      for (int i = 0; i < 4; i++) af[i] = *(const bf16x8*)(paB + i * 1024 + ko[kk]);
#pragma unroll
      for (int j = 0; j < 4; j++) bfv[j] = *(const bf16x8*)(pbB + j * 1024 + ko[kk]);
#pragma unroll
      for (int mi = 0; mi < 4; mi++)
#pragma unroll
        for (int ni = 0; ni < 4; ni++)
          acc[mi][ni] = __builtin_amdgcn_mfma_f32_16x16x32_bf16(af[mi], bfv[ni], acc[mi][ni], 0, 0, 0);
    }
  }

  const long row0 = rowA0 + waveM * 64 + (lane >> 4) * 4;
  const long col0 = rowB0 + waveN * 64 + (lane & 15);

  // ---- normal epilogue: P[row, col] = exp(acc - d_row), rowsums -> l ----
  float drow[4][4], lsum[4][4];
#pragma unroll
  for (int mi = 0; mi < 4; mi++)
#pragma unroll
    for (int r = 0; r < 4; r++) {
      drow[mi][r] = diag[row0 + mi * 16 + r];
      lsum[mi][r] = 0.f;
    }
  unsigned int nz = 0;
#pragma unroll
  for (int mi = 0; mi < 4; mi++)
#pragma unroll
    for (int ni = 0; ni < 4; ni++)
#pragma unroll
      for (int r = 0; r < 4; r++) {
        float pv = __expf(acc[mi][ni][r] - drow[mi][r]);
        unsigned short p16 = f2bf(pv);
        nz |= p16;
        lsum[mi][r] += bf2f(p16);
        P[(row0 + mi * 16 + r) * 4096 + col0 + ni * 16] = p16;
      }
#pragma unroll
  for (int off = 1; off < 16; off <<= 1)
#pragma unroll
    for (int mi = 0; mi < 4; mi++)
#pragma unroll
      for (int r = 0; r < 4; r++) lsum[mi][r] += __shfl_xor(lsum[mi][r], off, 64);
  if ((lane & 15) == 0) {
#pragma unroll
    for (int mi = 0; mi < 4; mi++)
#pragma unroll
      for (int r = 0; r < 4; r++)
        atomicAdd(&l[row0 + mi * 16 + r], lsum[mi][r]);
  }
  if (__ballot(nz != 0)) {
    if (lane == 0) {
      const int tile = bc * 2 + waveN;
      atomicOr(&flags[br * 2 + (tile >> 5)], 1u << (tile & 31));
    }
  }

  // ---- mirror epilogue (bc > br): P[col, row] = exp(acc - d_col) ----
  if (bc > br) {
    float dcol[4], csum[4];
#pragma unroll
    for (int ni = 0; ni < 4; ni++) {
      dcol[ni] = diag[col0 + ni * 16];
      csum[ni] = 0.f;
    }
    unsigned int nzm = 0;
#pragma unroll
    for (int mi = 0; mi < 4; mi++)
#pragma unroll
      for (int ni = 0; ni < 4; ni++) {
        ushort4 o;
        unsigned short x;
        float pv;
        pv = __expf(acc[mi][ni][0] - dcol[ni]); x = f2bf(pv); nzm |= x; csum[ni] += bf2f(x); o.x = x;
        pv = __expf(acc[mi][ni][1] - dcol[ni]); x = f2bf(pv); nzm |= x; csum[ni] += bf2f(x); o.y = x;
        pv = __expf(acc[mi][ni][2] - dcol[ni]); x = f2bf(pv); nzm |= x; csum[ni] += bf2f(x); o.z = x;
        pv = __expf(acc[mi][ni][3] - dcol[ni]); x = f2bf(pv); nzm |= x; csum[ni] += bf2f(x); o.w = x;
        *(ushort4*)(P + (col0 + ni * 16) * 4096 + row0 + mi * 16) = o;
      }
#pragma unroll
    for (int ni = 0; ni < 4; ni++) {
      csum[ni] += __shfl_xor(csum[ni], 16, 64);
      csum[ni] += __shfl_xor(csum[ni], 32, 64);
    }
    if (lane < 16) {
#pragma unroll
      for (int ni = 0; ni < 4; ni++)
        atomicAdd(&l[col0 + ni * 16], csum[ni]);
    }
    if (__ballot(nzm != 0)) {
      if (lane == 0) {
        const int tile = br * 2 + waveM;
        atomicOr(&flags[bc * 2 + (tile >> 5)], 1u << (tile & 31));
      }
    }
  }
}

// ---------- GEMM3 sparse: Z = (P @ Y) / l, skipping all-zero P tiles (exact) ----------
__global__ __launch_bounds__(256) void gemm3_sparse(
    const unsigned short* __restrict__ P, const unsigned short* __restrict__ Ybt,
    const float* __restrict__ l, const unsigned int* __restrict__ flags,
    float* __restrict__ Z) {
  __shared__ __align__(16) unsigned short smA[128 * 32];
  __shared__ __align__(16) unsigned short smB[64 * 32];
  const int tid = threadIdx.x, lane = tid & 63, wave = tid >> 6;
  const int waveM = wave >> 1, waveN = wave & 1;
  const long rowA0 = (long)blockIdx.y * 128;
  const long rowB0 = (long)blockIdx.x * 64;

  const int rS = tid >> 2;
  const int kS = (tid & 3) ^ swz(rS);
  const unsigned short* gA0 = P + (rowA0 + rS) * 4096 + kS * 8;
  const unsigned short* gA1 = gA0 + 64 * 4096;
  unsigned short* lA0 = &smA[tid * 8];
  const unsigned short* gB0 = Ybt + (rowB0 + rS) * 4096 + kS * 8;
  unsigned short* lB0 = &smB[tid * 8];

  const int ra = waveM * 64 + (lane & 15);
  const int rb = waveN * 32 + (lane & 15);
  const unsigned short* pa = &smA[(ra * 4 + ((lane >> 4) ^ swz(ra))) * 8];
  const unsigned short* pb = &smB[(rb * 4 + ((lane >> 4) ^ swz(rb))) * 8];

  const unsigned int f0 = flags[blockIdx.y * 2];
  const unsigned int f1 = flags[blockIdx.y * 2 + 1];

  f32x4 acc[4][2];
#pragma unroll
  for (int i = 0; i < 4; i++)
#pragma unroll
    for (int j = 0; j < 2; j++)
#pragma unroll
      for (int r = 0; r < 4; r++) acc[i][j][r] = 0.f;

  for (int t = 0; t < 64; ++t) {
    const unsigned int bit = (t < 32) ? ((f0 >> t) & 1u) : ((f1 >> (t - 32)) & 1u);
    if (!bit) continue;
#pragma unroll
    for (int kk = 0; kk < 2; ++kk) {
      const int k0 = t * 64 + kk * 32;
      __syncthreads();
      gld_lds16(gA0 + k0, lA0);
      gld_lds16(gA1 + k0, lA0 + 2048);
      gld_lds16(gB0 + k0, lB0);
      __syncthreads();
      bf16x8 af[4], bfv[2];
#pragma unroll
      for (int i = 0; i < 4; i++) af[i] = *(const bf16x8*)(pa + i * 512);
#pragma unroll
      for (int j = 0; j < 2; j++) bfv[j] = *(const bf16x8*)(pb + j * 512);
#pragma unroll
      for (int mi = 0; mi < 4; mi++)
#pragma unroll
        for (int ni = 0; ni < 2; ni++)
          acc[mi][ni] = __builtin_amdgcn_mfma_f32_16x16x32_bf16(af[mi], bfv[ni], acc[mi][ni], 0, 0, 0);
    }
  }

  const long row0 = rowA0 + waveM * 64 + (lane >> 4) * 4;
  const long col0 = rowB0 + waveN * 32 + (lane & 15);
#pragma unroll
  for (int mi = 0; mi < 4; mi++)
#pragma unroll
    for (int r = 0; r < 4; r++) {
      const long row = row0 + mi * 16 + r;
      const float inv = 1.f / l[row];
#pragma unroll
      for (int ni = 0; ni < 2; ni++)
        Z[row * 1024 + col0 + ni * 16] = acc[mi][ni][r] * inv;
    }
}

// ---------- launch ----------
extern "C" void kernel_launch(void* const* d_in, const int* in_sizes, int n_in,
                              void* d_out, int out_size, void* d_ws, size_t ws_size,
                              hipStream_t stream) {
  const float* Y = (const float*)d_in[0];   // 4096 x 1024
  const float* W = (const float*)d_in[1];   // 1024 x 1024
  float* Z = (float*)d_out;                 // 4096 x 1024 fp32

  uint8_t* w = (uint8_t*)d_ws;
  unsigned short* Yb   = (unsigned short*)(w);                         // 8 MB
  unsigned short* Ybt  = (unsigned short*)(w + (8ull  << 20));         // 8 MB
  unsigned short* Wb   = (unsigned short*)(w + (16ull << 20));         // 2 MB
  unsigned short* Gb   = (unsigned short*)(w + (18ull << 20));         // 8 MB
  unsigned short* P    = (unsigned short*)(w + (26ull << 20));         // 32 MB
  float*          diag = (float*)         (w + (58ull << 20));         // 16 KB
  float*          lrow = (float*)         (w + (58ull << 20) + 16384); // 16 KB
  unsigned int*   flg  = (unsigned int*)  (w + (58ull << 20) + 32768); // 256 B

  convert_all<<<dim3(64, 17), 256, 0, stream>>>(Y, Yb, Ybt, (const float4*)W,
                                                (ushort4*)Wb, diag);

  // G = Y * W^T (bf16) + diag accumulation; 128x64 tile, BK=64
  gemm1_fused<<<dim3(16, 32), 256, 0, stream>>>(Yb, Wb, Gb, diag);

  // P = exp(G G^T - diag[row]); triangle grid, 128x128 tile, BK=64
  gemm2_sym<<<528, 256, 0, stream>>>(Gb, diag, P, lrow, flg);

  // Z = (P @ Y) / l with exact zero-tile skipping
  gemm3_sparse<<<dim3(16, 32), 256, 0, stream>>>(P, Ybt, lrow, flg, Z);
}